// Round 3
// baseline (26.835 us; speedup 1.0000x reference)
//
#include <hip/hip_runtime.h>
#include <hip/hip_bf16.h>

// DIAGNOSTIC ROUND: identical kernel to R2, launched TWICE (idempotent).
// Marginal cost of 2nd dispatch = true steady-state kernel time, separating
// fixed launch/replay overhead from kernel-bound time.
//
// out[bt][s][d] = W_T[text[bt][s]][d] + b[d] + pe[s][d]

#define D_MODEL 1024
#define D4 (D_MODEL / 4)   // 256
#define SEQ 2048
#define TPB 4              // tokens per block

__global__ __launch_bounds__(256) void embed_kernel(
    const int* __restrict__ text,      // [8192]
    const float4* __restrict__ W_T,    // [50257][256]
    const float4* __restrict__ bias,   // [256]
    const float4* __restrict__ pe,     // [4096][256]
    float4* __restrict__ out)          // [8192][256]
{
    const int d4   = threadIdx.x;          // 0..255
    const int base = blockIdx.x * TPB;     // first token of this block

    const float4 bb = bias[d4];

    int rows[TPB];
    #pragma unroll
    for (int t = 0; t < TPB; ++t)
        rows[t] = text[base + t];          // block-uniform -> scalar loads

    float4 w[TPB];
    #pragma unroll
    for (int t = 0; t < TPB; ++t)
        w[t] = W_T[(size_t)rows[t] * D4 + d4];

    float4 p[TPB];
    #pragma unroll
    for (int t = 0; t < TPB; ++t)
        p[t] = pe[(size_t)((base + t) & (SEQ - 1)) * D4 + d4];

    #pragma unroll
    for (int t = 0; t < TPB; ++t) {
        float4 o;
        o.x = w[t].x + bb.x + p[t].x;
        o.y = w[t].y + bb.y + p[t].y;
        o.z = w[t].z + bb.z + p[t].z;
        o.w = w[t].w + bb.w + p[t].w;
        out[(size_t)(base + t) * D4 + d4] = o;
    }
}

extern "C" void kernel_launch(void* const* d_in, const int* in_sizes, int n_in,
                              void* d_out, int out_size, void* d_ws, size_t ws_size,
                              hipStream_t stream) {
    const int*    text = (const int*)d_in[0];      // [4*2048]
    const float4* W_T  = (const float4*)d_in[1];   // [50257*1024] f32
    const float4* bias = (const float4*)d_in[2];   // [1024] f32
    const float4* pe   = (const float4*)d_in[3];   // [1*4096*1024] f32
    float4* out = (float4*)d_out;

    const int n_tokens = in_sizes[0];              // 8192

    // Launch twice: marginal cost of the 2nd = steady-state kernel time.
    embed_kernel<<<n_tokens / TPB, 256, 0, stream>>>(text, W_T, bias, pe, out);
    embed_kernel<<<n_tokens / TPB, 256, 0, stream>>>(text, W_T, bias, pe, out);
}

// Round 4
// 17.098 us; speedup vs baseline: 1.5695x; 1.5695x over previous
//
#include <hip/hip_runtime.h>
#include <hip/hip_bf16.h>

// out[b][s][d] = W_T[text[b][s]][d] + bias[d] + pe[s][d]
// B=4, S=2048, D=1024, VOCAB=50257. All f32 except text (int32).
//
// One block per sequence position s (2048 blocks, 256 threads).
// Each block handles s for ALL 4 batch elements: pe[s] is loaded ONCE and
// reused 4x in-register (minimal pe traffic, 8 MB), 4 independent W_T
// gathers per lane give load ILP. Traffic floor: 32 MB gather + 8 MB pe
// + 33.5 MB write = 73.5 MB @ ~6.3 TB/s ~= 11.6 us kernel + ~5 us fixed
// replay overhead.

#define D_MODEL 1024
#define D4 (D_MODEL / 4)   // 256
#define SEQ 2048
#define BATCH 4

__global__ __launch_bounds__(256) void embed_kernel(
    const int* __restrict__ text,      // [4][2048]
    const float4* __restrict__ W_T,    // [50257][256]
    const float4* __restrict__ bias,   // [256]
    const float4* __restrict__ pe,     // [4096][256]
    float4* __restrict__ out)          // [4][2048][256]
{
    const int d4 = threadIdx.x;        // 0..255
    const int s  = blockIdx.x;         // 0..2047

    const float4 bb = bias[d4];
    const float4 p  = pe[(size_t)s * D4 + d4];   // loaded once, reused 4x

    int rows[BATCH];
    #pragma unroll
    for (int b = 0; b < BATCH; ++b)
        rows[b] = text[b * SEQ + s];   // block-uniform -> scalar loads

    float4 w[BATCH];
    #pragma unroll
    for (int b = 0; b < BATCH; ++b)
        w[b] = W_T[(size_t)rows[b] * D4 + d4];

    #pragma unroll
    for (int b = 0; b < BATCH; ++b) {
        float4 o;
        o.x = w[b].x + bb.x + p.x;
        o.y = w[b].y + bb.y + p.y;
        o.z = w[b].z + bb.z + p.z;
        o.w = w[b].w + bb.w + p.w;
        out[(size_t)(b * SEQ + s) * D4 + d4] = o;
    }
}

extern "C" void kernel_launch(void* const* d_in, const int* in_sizes, int n_in,
                              void* d_out, int out_size, void* d_ws, size_t ws_size,
                              hipStream_t stream) {
    const int*    text = (const int*)d_in[0];      // [4*2048]
    const float4* W_T  = (const float4*)d_in[1];   // [50257*1024] f32
    const float4* bias = (const float4*)d_in[2];   // [1024] f32
    const float4* pe   = (const float4*)d_in[3];   // [1*4096*1024] f32
    float4* out = (float4*)d_out;

    embed_kernel<<<SEQ, 256, 0, stream>>>(text, W_T, bias, pe, out);
}

// Round 5
// 15.907 us; speedup vs baseline: 1.6869x; 1.0749x over previous
//
#include <hip/hip_runtime.h>
#include <hip/hip_bf16.h>

// out[bt][s][d] = W_T[text[bt][s]][d] + b[d] + pe[s][d]
// B=4, S=2048, D=1024, VOCAB=50257. All f32 except text (int32).
// One block per token row (8192 rows), 256 threads x float4 = 4KB row.
//
// ROOFLINE NOTE (R3 diagnostic): marginal kernel time = 11.0 us for
// ~73.5 MB compulsory traffic (32 MB W_T gather + 8 MB pe + 33.5 MB write)
// = 6.7 TB/s effective, at the ~6.3 TB/s achievable HBM ceiling. The
// remaining ~4.9 us of dur_us is fixed dispatch/graph-replay overhead.
// R4's batch-grouped variant (pe loaded once, writes 8 MB apart) regressed
// to 17.1 us -> contiguous token-major writes win at the HBM floor.

#define D_MODEL 1024
#define D4 (D_MODEL / 4)   // 256
#define SEQ 2048

__global__ __launch_bounds__(256) void embed_kernel(
    const int* __restrict__ text,      // [8192]
    const float4* __restrict__ W_T,    // [50257][256]
    const float4* __restrict__ bias,   // [256]
    const float4* __restrict__ pe,     // [4096][256] (use first 2048 rows)
    float4* __restrict__ out)          // [8192][256]
{
    const int token = blockIdx.x;       // 0..8191
    const int d4    = threadIdx.x;      // 0..255
    const int s     = token & (SEQ - 1);

    const int row = text[token];        // uniform within block -> cached broadcast

    const float4 w = W_T[(size_t)row * D4 + d4];
    const float4 bb = bias[d4];
    const float4 p = pe[(size_t)s * D4 + d4];

    float4 o;
    o.x = w.x + bb.x + p.x;
    o.y = w.y + bb.y + p.y;
    o.z = w.z + bb.z + p.z;
    o.w = w.w + bb.w + p.w;

    out[(size_t)token * D4 + d4] = o;
}

extern "C" void kernel_launch(void* const* d_in, const int* in_sizes, int n_in,
                              void* d_out, int out_size, void* d_ws, size_t ws_size,
                              hipStream_t stream) {
    const int*    text = (const int*)d_in[0];      // [4*2048]
    const float4* W_T  = (const float4*)d_in[1];   // [50257*1024] f32
    const float4* bias = (const float4*)d_in[2];   // [1024] f32
    const float4* pe   = (const float4*)d_in[3];   // [1*4096*1024] f32
    float4* out = (float4*)d_out;

    const int n_tokens = in_sizes[0];              // 8192
    embed_kernel<<<n_tokens, 256, 0, stream>>>(text, W_T, bias, pe, out);
}